// Round 18
// baseline (497.839 us; speedup 1.0000x reference)
//
#include <hip/hip_runtime.h>
#include <hip/hip_bf16.h>
#include <cstddef>

// Problem constants
#define BB    32
#define IMG   224
#define CIN   3
#define ED    64
#define TD    64
#define MM    32
#define HP    56
#define TT    3136      // 56*56
#define C4    256       // 4*ED
#define KQVN  192       // 3*TD

typedef __attribute__((ext_vector_type(8))) short bf16x8;
typedef __attribute__((ext_vector_type(4))) float f32x4;

// workspace offsets (float units). v/kp/qp bf16. Temporal plan (R17 FIX):
//  prm_conv1 writes xn[6.42M,19.27M) AND c1b[19.27M,32.11M) FIRST, so c2b may
//  NOT alias xn. convXb (bf16) only uses [0,3.21M) -> c2b moved to [3.21M,6.42M).
#define OFF_CONVX  0u           // convXb bf16: 6,422,528 elems = [0, 3,211,264) f
#define OFF_C2B    3211264u     // c2b bf16: 6,422,528 elems = [3.21M, 6.42M) f  (FIX R17)
#define OFF_XN     6422528u     // 12,845,056 f (25,690,112 bf16)
#define OFF_C1B    19267584u    // bf16; dead after conv2, then v/kp/qp overwrite
#define OFF_V      19267584u    // bf16 (6,422,528 elems = 3,211,264 f used)
#define OFF_KP     25690112u    // bf16
#define OFF_QP     28901376u    // bf16
#define OFF_PART   32112640u    // 1,048,576 f
#define OFF_KPTV   33161216u    // region 65,536 f
#define OFF_KPSP   (OFF_KPTV + 32768u)
#define OFF_WPJB   (OFF_KPTV + 49152u)
#define OFF_WM1B   (OFF_KPTV + 51200u)
#define OFF_WM2B   (OFF_KPTV + 53248u)
#define OFF_WPFH   (OFF_KPTV + 55296u)
#define OFF_WPFL   (OFF_KPTV + 56320u)
#define OFF_KPSUM  33226752u    // 1,024 f
// weights aliased into PART region (dead once k_kptv writes part)
#define OFF_WPT    (OFF_PART)             // 37,632 f
#define OFF_WKB    (OFF_PART + 37632u)    // 24,576 f
#define OFF_WC2B   (OFF_PART + 62208u)    // 18,432 f
#define OFF_WT3B   (OFF_PART + 80640u)    // 18,432 f
#define OFF_WC1B   (OFF_PART + 99072u)    // 1,024 f
// total 33,227,776 f = 132.9 MB

__device__ __forceinline__ float geluf(float v){
  return 0.5f*v*(1.f + erff(v*0.70710678118654752f));
}
__device__ __forceinline__ float siluf(float v){
  return v/(1.f + expf(-v));
}
__device__ __forceinline__ ushort bfbits(float v){
  __hip_bfloat16 h = __float2bfloat16(v);
  return *reinterpret_cast<ushort*>(&h);
}
__device__ __forceinline__ float bf2f(ushort u){
  return __uint_as_float(((unsigned)u) << 16);
}

// ---------------- weight transposes / casts
__global__ __launch_bounds__(256) void k_wtrans(
    const float* __restrict__ prm_w, const float* __restrict__ kqv_w,
    const float* __restrict__ pcm_w2, const float* __restrict__ pcm_w3,
    const float* __restrict__ pcm_w1, const float* __restrict__ proj_w,
    const float* __restrict__ mlp_w1, const float* __restrict__ mlp_w2,
    const float* __restrict__ wperf,
    float* __restrict__ wpt, __hip_bfloat16* __restrict__ wkb,
    __hip_bfloat16* __restrict__ wc2b, __hip_bfloat16* __restrict__ wt3b,
    __hip_bfloat16* __restrict__ wc1b, __hip_bfloat16* __restrict__ wpjb,
    __hip_bfloat16* __restrict__ wm1b, __hip_bfloat16* __restrict__ wm2b,
    __hip_bfloat16* __restrict__ wpfh, __hip_bfloat16* __restrict__ wpfl)
{
  int idx = blockIdx.x*256 + threadIdx.x;
  if (idx < 37632){
    int oc = idx & 63, r = idx >> 6;        // r = i*147+tap
    int i = r/147, tap = r - i*147;
    wpt[idx] = prm_w[(i*64 + oc)*147 + tap];
  } else if (idx < 86784){
    int i4 = idx - 37632;
    wkb[i4] = __float2bfloat16(kqv_w[i4]);
  } else if (idx < 123648){
    int i2 = idx - 86784;                   // wc2b[oc][ (kh*3+kw)*64+ci ]
    int oc = i2/576, rem = i2 - oc*576;
    int khkw = rem >> 6, ci = rem & 63;
    int kh = khkw/3, kw = khkw - kh*3;
    wc2b[i2] = __float2bfloat16(pcm_w2[(oc*64+ci)*9 + kh*3 + kw]);
  } else if (idx < 160512){
    int i3 = idx - 123648;
    int oc = i3/576, rem = i3 - oc*576;
    int khkw = rem >> 6, ci = rem & 63;
    int kh = khkw/3, kw = khkw - kh*3;
    wt3b[i3] = __float2bfloat16(pcm_w3[(oc*64+ci)*9 + kh*3 + kw]);
  } else if (idx < 162560){
    int i5 = idx - 160512;                  // wc1b[oc][k], k pad32
    int oc = i5 >> 5, k = i5 & 31;
    float v = 0.f;
    if (k < 27) v = pcm_w1[oc*27 + k];
    wc1b[i5] = __float2bfloat16(v);
  } else if (idx < 166656){
    wpjb[idx - 162560] = __float2bfloat16(proj_w[idx - 162560]);
  } else if (idx < 170752){
    wm1b[idx - 166656] = __float2bfloat16(mlp_w1[idx - 166656]);
  } else if (idx < 174848){
    wm2b[idx - 170752] = __float2bfloat16(mlp_w2[idx - 170752]);
  } else if (idx < 176896){
    int i6 = idx - 174848;                  // wperf hi [m][c]
    wpfh[i6] = __float2bfloat16(wperf[i6]);
  } else if (idx < 178944){
    int i7 = idx - 176896;                  // wperf lo residual
    float v = wperf[i7];
    float h = bf2f(bfbits(v));
    wpfl[i7] = __float2bfloat16(v - h);
  }
}

// ---------------- PRM conv core: phase-major layout, wave-uniform broadcast reads.
#define LOADX(PH) do{ const float4* xr_ = (const float4*)(rowb + (PH)*20); \
  *(float4*)&X[0]=xr_[0]; *(float4*)&X[4]=xr_[1]; *(float4*)&X[8]=xr_[2]; \
  *(float4*)&X[12]=xr_[3]; *(float4*)&X[16]=xr_[4]; }while(0)
#define TAP(KW,Q0) do{ const float wv_ = wrow[(KW)*64]; \
  v[0]+=wv_*X[(Q0)+0];  v[1]+=wv_*X[(Q0)+1];  v[2]+=wv_*X[(Q0)+2];  v[3]+=wv_*X[(Q0)+3]; \
  v[4]+=wv_*X[(Q0)+4];  v[5]+=wv_*X[(Q0)+5];  v[6]+=wv_*X[(Q0)+6];  v[7]+=wv_*X[(Q0)+7]; \
  v[8]+=wv_*X[(Q0)+8];  v[9]+=wv_*X[(Q0)+9];  v[10]+=wv_*X[(Q0)+10]; v[11]+=wv_*X[(Q0)+11]; \
  v[12]+=wv_*X[(Q0)+12]; v[13]+=wv_*X[(Q0)+13]; }while(0)

template<int D>
__device__ __forceinline__ void prm_core(const float* __restrict__ xt2,
    const float* __restrict__ wq, float v[14])
{
  constexpr int R0 = 12 - 3*D;
  #pragma unroll 1
  for (int ci=0; ci<3; ++ci){
    #pragma unroll 1
    for (int kh=0; kh<7; ++kh){
      const float* rowb = xt2 + ci*2000 + (R0 + kh*D)*80;
      const float* wrow = wq + ((ci*7+kh)*7)*64;
      float X[20];
      if constexpr (D == 1){
        LOADX(0); TAP(3,3);
        LOADX(1); TAP(0,2); TAP(4,3);
        LOADX(2); TAP(1,2); TAP(5,3);
        LOADX(3); TAP(2,2); TAP(6,3);
      } else if constexpr (D == 2){
        LOADX(0); TAP(1,2); TAP(3,3); TAP(5,4);
        LOADX(2); TAP(0,1); TAP(2,2); TAP(4,3); TAP(6,4);
      } else if constexpr (D == 3){
        LOADX(0); TAP(3,3);
        LOADX(1); TAP(2,2); TAP(6,5);
        LOADX(2); TAP(1,1); TAP(5,4);
        LOADX(3); TAP(0,0); TAP(4,3);
      } else {
        LOADX(0); TAP(0,0); TAP(1,1); TAP(2,2); TAP(3,3); TAP(4,4); TAP(5,5); TAP(6,6);
      }
    }
  }
}

// ---------------- FUSED: prm_ln (7168 blocks, VALU) + conv1 (6272 blocks, MFMA)
// interleave 15-block groups: 8 prm + 7 conv1 (13440 = 896*15 exactly)
__global__ __launch_bounds__(256) void k_prm_conv1(
    const float* __restrict__ x, const float* __restrict__ wpt,
    const float* __restrict__ prm_b, const float* __restrict__ ln_g,
    const float* __restrict__ ln_b, __hip_bfloat16* __restrict__ xn,
    const __hip_bfloat16* __restrict__ wc1b, const float* __restrict__ c1bias,
    __hip_bfloat16* __restrict__ c1b)
{
  __shared__ __align__(16) char fsm[24448];   // prm: xt2[6000]f ; conv1: xs+As
  __shared__ float wred[4][14][2];
  const int t = threadIdx.x;
  const int group = blockIdx.x/15, r15 = blockIdx.x - group*15;

  if (r15 < 8){
    // ---------------- PRM + LN body ----------------
    float* xt2 = (float*)fsm;
    const int pid = group*8 + r15;            // 0..7167
    const int b = pid/224, rest = pid - b*224;
    const int oh  = rest >> 2;
    const int owt = rest & 3;
    const int ow0 = owt*14;
    const int ih0 = oh*4 - 11;
    const int iw0 = ow0*4 - 11;

    const float* xb = x + (size_t)b*CIN*IMG*IMG;
    for (int idx = t; idx < 6000; idx += 256){
      int ci  = idx / 2000;
      int rem = idx - ci*2000;
      int r   = rem / 80;
      int cc  = rem - r*80;
      int ih = ih0 + r, iw = iw0 + cc;
      float val = 0.f;
      if ((unsigned)ih < (unsigned)IMG && (unsigned)iw < (unsigned)IMG)
        val = xb[(ci*IMG+ih)*IMG+iw];
      xt2[(ci*25 + r)*80 + (cc&3)*20 + (cc>>2)] = val;
    }
    __syncthreads();

    const int i = t >> 6, lane = t & 63;
    float v[14];
    const float bi = prm_b[i*64+lane];
    #pragma unroll
    for (int p=0;p<14;++p) v[p] = bi;
    const float* wq = wpt + (i*147)*64 + lane;

    if      (i == 0) prm_core<1>(xt2, wq, v);
    else if (i == 1) prm_core<2>(xt2, wq, v);
    else if (i == 2) prm_core<3>(xt2, wq, v);
    else             prm_core<4>(xt2, wq, v);

    #pragma unroll
    for (int p=0;p<14;++p) v[p] = geluf(v[p]);
    #pragma unroll
    for (int p=0;p<14;++p){
      float s1 = v[p], s2 = v[p]*v[p];
      #pragma unroll
      for (int o=32;o;o>>=1){
        s1 += __shfl_xor(s1, o, 64);
        s2 += __shfl_xor(s2, o, 64);
      }
      if (lane == 0){ wred[i][p][0] = s1; wred[i][p][1] = s2; }
    }
    __syncthreads();
    const float lg = ln_g[t], lb = ln_b[t];
    const int s_base = oh*HP + ow0;
    #pragma unroll
    for (int p=0;p<14;++p){
      float S1 = wred[0][p][0]+wred[1][p][0]+wred[2][p][0]+wred[3][p][0];
      float S2 = wred[0][p][1]+wred[1][p][1]+wred[2][p][1]+wred[3][p][1];
      float mu = S1*(1.f/256.f);
      float rs = rsqrtf(S2*(1.f/256.f) - mu*mu + 1e-5f);
      float outv = (v[p]-mu)*rs*lg + lb;
      xn[((size_t)(b*TT + s_base + p))*256 + t] = __float2bfloat16(outv);
    }
  } else {
    // ---------------- conv1 (MFMA implicit GEMM) body ----------------
    ushort* xs = (ushort*)fsm;                 // [3][17][18] = 1836 us
    ushort* As = (ushort*)(fsm + 4096);        // [64][40] = 2560 us
    const int cid = group*7 + (r15 - 8);       // 0..6271
    const int b = cid/196, s196 = cid - b*196;
    const int th = s196/14, tw = s196 - th*14;
    const int oh0 = th*8, ow0 = tw*8;
    const int ih0 = oh0*2 - 1, iw0 = ow0*2 - 1;
    const int w = t>>6, lane = t&63, l15 = lane&15, hi = lane>>4;

    const float* xb = x + (size_t)b*CIN*IMG*IMG;
    for (int idx = t; idx < 918; idx += 256){
      int ci = idx/306, rem = idx - ci*306;
      int r = rem/18, c = rem - r*18;
      float v = 0.f;
      int ih = ih0 + r, iw = iw0 + c;
      if (c < 17 && (unsigned)ih < 224u && (unsigned)iw < 224u)
        v = xb[(ci*IMG+ih)*IMG+iw];
      xs[idx] = bfbits(v);
    }
    __syncthreads();
    for (int idx = t; idx < 2048; idx += 256){
      int pos = idx >> 5, k = idx & 31;
      ushort v = 0;
      if (k < 27){
        int ci = k/9, rem = k - ci*9;
        int kh = rem/3, kw = rem - kh*3;
        v = xs[(ci*17 + (pos>>3)*2 + kh)*18 + (pos&7)*2 + kw];
      }
      As[pos*40 + k] = v;
    }
    __syncthreads();

    float bs4[4];
    #pragma unroll
    for (int nb=0;nb<4;++nb) bs4[nb] = c1bias[nb*16+l15];
    f32x4 acc[4];
    #pragma unroll
    for (int nb=0;nb<4;++nb) acc[nb] = (f32x4){0.f,0.f,0.f,0.f};
    const ushort* wq = (const ushort*)wc1b;
    {
      bf16x8 a = *(const bf16x8*)&As[(w*16+l15)*40 + hi*8];
      #pragma unroll
      for (int nb=0;nb<4;++nb){
        bf16x8 bv = *(const bf16x8*)&wq[(nb*16+l15)*32 + hi*8];
        acc[nb] = __builtin_amdgcn_mfma_f32_16x16x32_bf16(a, bv, acc[nb], 0, 0, 0);
      }
    }
    #pragma unroll
    for (int nb=0;nb<4;++nb){
      #pragma unroll
      for (int r=0;r<4;++r){
        int row = w*16 + hi*4 + r;
        int oh = oh0 + (row>>3), ow = ow0 + (row&7);
        c1b[(((size_t)b*112+oh)*112+ow)*64 + nb*16+l15] =
          __float2bfloat16(siluf(acc[nb][r] + bs4[nb]));
      }
    }
  }
}

// ---------------- conv2 (MFMA implicit GEMM): c1b -> c2b NHWC bf16, 3x3 s2 p1, BN+SiLU
__global__ __launch_bounds__(256) void k_conv2(
    const __hip_bfloat16* __restrict__ c1b, const __hip_bfloat16* __restrict__ wc2b,
    const float* __restrict__ bias, const float* __restrict__ g,
    const float* __restrict__ bb, const float* __restrict__ mean,
    const float* __restrict__ var, __hip_bfloat16* __restrict__ c2b)
{
  __shared__ __align__(16) ushort xs[17*17*72];
  const int b = blockIdx.y;
  const int th = blockIdx.x/7, tw = blockIdx.x - th*7;
  const int oh0 = th*8, ow0 = tw*8;
  const int t = threadIdx.x;
  const int w = t>>6, lane = t&63, l15 = lane&15, hi = lane>>4;

  const int ih0 = oh0*2-1, iw0 = ow0*2-1;
  const ushort* c1u = (const ushort*)c1b;
  for (int seg = t; seg < 2312; seg += 256){
    int pos = seg >> 3, s8 = seg & 7;
    int r = pos/17, c = pos - r*17;
    int ih = ih0 + r, iw = iw0 + c;
    uint4 val = {0,0,0,0};
    if ((unsigned)ih < 112u && (unsigned)iw < 112u)
      val = *(const uint4*)&c1u[(((size_t)b*112+ih)*112+iw)*64 + s8*8];
    *(uint4*)&xs[(r*17+c)*72 + s8*8] = val;
  }
  __syncthreads();

  float bs4[4], iv4[4], mn4[4], bo4[4];
  #pragma unroll
  for (int nb=0;nb<4;++nb){
    int oc = nb*16+l15;
    bs4[nb] = bias[oc];
    iv4[nb] = g[oc]*rsqrtf(var[oc]+1e-5f);
    mn4[nb] = mean[oc];
    bo4[nb] = bb[oc];
  }

  f32x4 acc[4];
  #pragma unroll
  for (int nb=0;nb<4;++nb) acc[nb] = (f32x4){0.f,0.f,0.f,0.f};

  const int p = w*16 + l15, pr = p>>3, pc = p&7;
  const ushort* wq = (const ushort*)wc2b;

  for (int ks=0; ks<18; ++ks){
    const int k0 = ks*32 + hi*8;
    const int khkw = k0 >> 6, ci0 = k0 & 63;
    const int kh = khkw/3, kw = khkw - kh*3;
    bf16x8 a = *(const bf16x8*)&xs[((2*pr+kh)*17 + 2*pc+kw)*72 + ci0];
    #pragma unroll
    for (int nb=0;nb<4;++nb){
      bf16x8 bv = *(const bf16x8*)&wq[(nb*16+l15)*576 + k0];
      acc[nb] = __builtin_amdgcn_mfma_f32_16x16x32_bf16(a, bv, acc[nb], 0, 0, 0);
    }
  }

  #pragma unroll
  for (int nb=0;nb<4;++nb){
    #pragma unroll
    for (int r=0;r<4;++r){
      int pp = w*16 + hi*4 + r;
      int oh = oh0 + (pp>>3), ow = ow0 + (pp&7);
      float vv = acc[nb][r] + bs4[nb];
      vv = (vv - mn4[nb])*iv4[nb] + bo4[nb];
      c2b[(((size_t)b*56+oh)*56+ow)*64 + nb*16+l15] = __float2bfloat16(siluf(vv));
    }
  }
}

// ---------------- conv3 (MFMA implicit GEMM): c2b -> convXb (bf16 NHWC), 3x3 s1 p1, SiLU
__global__ __launch_bounds__(256) void k_conv3(
    const __hip_bfloat16* __restrict__ c2b, const __hip_bfloat16* __restrict__ wt3b,
    const float* __restrict__ bias, __hip_bfloat16* __restrict__ convXb)
{
  __shared__ __align__(16) ushort xs[10*12*72];
  const int b = blockIdx.y;
  const int th = blockIdx.x/7, tw = blockIdx.x - th*7;
  const int oh0 = th*8, ow0 = tw*8;
  const int t = threadIdx.x;
  const int w = t>>6, lane = t&63, l15 = lane&15, hi = lane>>4;

  const ushort* c2u = (const ushort*)c2b;
  for (int seg = t; seg < 960; seg += 256){
    int pos = seg >> 3, s8 = seg & 7;
    int r = pos/12, c = pos - r*12;
    int ih = oh0 - 1 + r, iw = ow0 - 1 + c;
    uint4 val = {0,0,0,0};
    if ((unsigned)ih < 56u && (unsigned)iw < 56u)
      val = *(const uint4*)&c2u[(((size_t)b*56+ih)*56+iw)*64 + s8*8];
    *(uint4*)&xs[(r*12+c)*72 + s8*8] = val;
  }
  __syncthreads();

  float bs4[4];
  #pragma unroll
  for (int nb=0;nb<4;++nb) bs4[nb] = bias[nb*16+l15];

  f32x4 acc[4];
  #pragma unroll
  for (int nb=0;nb<4;++nb) acc[nb] = (f32x4){0.f,0.f,0.f,0.f};

  const int p = w*16 + l15, pr = p>>3, pc = p&7;
  const ushort* wq = (const ushort*)wt3b;

  for (int ks=0; ks<18; ++ks){
    const int k0 = ks*32 + hi*8;
    const int khkw = k0 >> 6, ci0 = k0 & 63;
    const int kh = khkw/3, kw = khkw - kh*3;
    bf16x8 a = *(const bf16x8*)&xs[((pr+kh)*12 + pc+kw)*72 + ci0];
    #pragma unroll
    for (int nb=0;nb<4;++nb){
      bf16x8 bv = *(const bf16x8*)&wq[(nb*16+l15)*576 + k0];
      acc[nb] = __builtin_amdgcn_mfma_f32_16x16x32_bf16(a, bv, acc[nb], 0, 0, 0);
    }
  }

  #pragma unroll
  for (int nb=0;nb<4;++nb){
    #pragma unroll
    for (int r=0;r<4;++r){
      int pp = w*16 + hi*4 + r;
      int oh = oh0 + (pp>>3), ow = ow0 + (pp&7);
      int s = oh*HP + ow;
      convXb[((size_t)b*TT + s)*64 + nb*16+l15] =
        __float2bfloat16(siluf(acc[nb][r] + bs4[nb]));
    }
  }
}

// ---------------- KQV GEMM (bf16 MFMA) + Performer feature map (bf16-split MFMA dots)
__global__ __launch_bounds__(256) void k_kqv_perf(
    const __hip_bfloat16* __restrict__ xn, const __hip_bfloat16* __restrict__ wkb,
    const float* __restrict__ kqv_b,
    const __hip_bfloat16* __restrict__ wpfh, const __hip_bfloat16* __restrict__ wpfl,
    __hip_bfloat16* __restrict__ v_g, __hip_bfloat16* __restrict__ kp,
    __hip_bfloat16* __restrict__ qp)
{
  __shared__ __align__(16) char smem[36864];
  __shared__ __align__(16) ushort wph[32*72];
  __shared__ __align__(16) ushort wpl[32*72];
  __shared__ float kqvb_s[192];
  __shared__ float xd_s[128];
  ushort* As  = (ushort*)smem;
  ushort* Bs  = (ushort*)(smem + 9216);
  ushort* zhb = (ushort*)smem;
  ushort* zlb = (ushort*)(smem + 18432);

  const int t = threadIdx.x;
  const int m0 = blockIdx.x*64;
  const int w = t >> 6, lane = t & 63;
  const int l15 = lane & 15, hi = lane >> 4;

  const ushort* wph_g = (const ushort*)wpfh;
  const ushort* wpl_g = (const ushort*)wpfl;
  for (int idx = t; idx < 2048; idx += 256){
    int row = idx >> 6, c = idx & 63;
    wph[row*72 + c] = wph_g[idx];
    wpl[row*72 + c] = wpl_g[idx];
  }
  if (t < 192) kqvb_s[t] = kqv_b[t];

  f32x4 acc[12];
  #pragma unroll
  for (int nb=0;nb<12;++nb) acc[nb] = (f32x4){0.f,0.f,0.f,0.f};

  const ushort* xnu = (const ushort*)xn;
  const ushort* wku = (const ushort*)wkb;

  for (int kc=0; kc<4; ++kc){
    #pragma unroll
    for (int ss=0; ss<2; ++ss){
      int seg = ss*256 + t;
      int row = seg >> 3, c8 = seg & 7;
      *(uint4*)&As[row*72 + c8*8] =
        *(const uint4*)&xnu[((size_t)(m0+row))*256 + kc*64 + c8*8];
    }
    #pragma unroll
    for (int ss=0; ss<6; ++ss){
      int seg = ss*256 + t;
      int row = seg >> 3, c8 = seg & 7;
      *(uint4*)&Bs[row*72 + c8*8] =
        *(const uint4*)&wku[row*256 + kc*64 + c8*8];
    }
    __syncthreads();
    #pragma unroll
    for (int ks=0; ks<2; ++ks){
      bf16x8 a = *(const bf16x8*)&As[(16*w + l15)*72 + ks*32 + hi*8];
      #pragma unroll
      for (int nb=0;nb<12;++nb){
        bf16x8 bv = *(const bf16x8*)&Bs[(nb*16 + l15)*72 + ks*32 + hi*8];
        acc[nb] = __builtin_amdgcn_mfma_f32_16x16x32_bf16(a, bv, acc[nb], 0, 0, 0);
      }
    }
    __syncthreads();
  }

  // scatter: k,q -> zhb/zlb (bf16 split); v -> global bf16 (+bias)
  #pragma unroll
  for (int nb=0;nb<12;++nb){
    int col = nb*16 + l15;
    float bias = kqvb_s[col];
    #pragma unroll
    for (int r=0;r<4;++r){
      int row = w*16 + hi*4 + r;
      float val = acc[nb][r] + bias;
      if (col < 128){
        int zrow = (col >> 6)*64 + row;
        int zc = col & 63;
        ushort zh = bfbits(val);
        zhb[zrow*72 + zc] = zh;
        zlb[zrow*72 + zc] = bfbits(val - bf2f(zh));
      } else {
        ((ushort*)v_g)[((size_t)(m0+row))*64 + (col-128)] = bfbits(val);
      }
    }
  }
  __syncthreads();

  if (t < 128){
    float s = 0.f;
    #pragma unroll
    for (int c8=0;c8<8;++c8){
      bf16x8 zh8 = *(const bf16x8*)&zhb[t*72 + c8*8];
      bf16x8 zl8 = *(const bf16x8*)&zlb[t*72 + c8*8];
      #pragma unroll
      for (int j=0;j<8;++j){
        float z = bf2f((ushort)zh8[j]) + bf2f((ushort)zl8[j]);
        s += z*z;
      }
    }
    xd_s[t] = 0.5f*s;
  }
  __syncthreads();

  // dots MFMA: M=128, N=32, K=64; wh*zh + wh*zl + wl*zh
  f32x4 accd[2][2];
  #pragma unroll
  for (int ri=0;ri<2;++ri)
    #pragma unroll
    for (int nb=0;nb<2;++nb) accd[ri][nb] = (f32x4){0.f,0.f,0.f,0.f};
  #pragma unroll
  for (int ri=0;ri<2;++ri){
    const int rb = 2*w + ri;
    #pragma unroll
    for (int ks=0;ks<2;++ks){
      bf16x8 ah = *(const bf16x8*)&zhb[(rb*16 + l15)*72 + ks*32 + hi*8];
      bf16x8 al = *(const bf16x8*)&zlb[(rb*16 + l15)*72 + ks*32 + hi*8];
      #pragma unroll
      for (int nb=0;nb<2;++nb){
        bf16x8 bh = *(const bf16x8*)&wph[(nb*16 + l15)*72 + ks*32 + hi*8];
        bf16x8 bl = *(const bf16x8*)&wpl[(nb*16 + l15)*72 + ks*32 + hi*8];
        accd[ri][nb] = __builtin_amdgcn_mfma_f32_16x16x32_bf16(ah, bh, accd[ri][nb], 0, 0, 0);
        accd[ri][nb] = __builtin_amdgcn_mfma_f32_16x16x32_bf16(al, bh, accd[ri][nb], 0, 0, 0);
        accd[ri][nb] = __builtin_amdgcn_mfma_f32_16x16x32_bf16(ah, bl, accd[ri][nb], 0, 0, 0);
      }
    }
  }
  #pragma unroll
  for (int ri=0;ri<2;++ri){
    const int rb = 2*w + ri;
    #pragma unroll
    for (int nb=0;nb<2;++nb){
      const int m = nb*16 + l15;
      #pragma unroll
      for (int r=0;r<4;++r){
        int row = rb*16 + hi*4 + r;
        int wh = row >> 6, pos = row & 63;
        float outv = expf(accd[ri][nb][r] - xd_s[row]) * 0.17677669529663687f;
        ushort* dst = (ushort*)(wh ? qp : kp);
        dst[((size_t)(m0+pos))*32 + m] = bfbits(outv);
      }
    }
  }
}

// ---------------- kptv (MFMA): part = v^T kp per 196-chunk; bf16 inputs
__global__ __launch_bounds__(256) void k_kptv(
    const __hip_bfloat16* __restrict__ v_g, const __hip_bfloat16* __restrict__ kp,
    float* __restrict__ part, float* __restrict__ kpsum_part)
{
  __shared__ __align__(16) ushort vT[64*232];
  __shared__ __align__(16) ushort kpT[32*232];
  __shared__ float ksh[8][32];
  const int b = blockIdx.y, g = blockIdx.x;
  const int t = threadIdx.x;
  const int w = t>>6, lane = t&63, l15 = lane&15, hi = lane>>4;
  const int t0 = g*196;
  const ushort* vu = (const ushort*)v_g;
  const ushort* ku = (const ushort*)kp;

  for (int idx = t; idx < 14336; idx += 256){
    int tt = idx >> 6, n = idx & 63;
    vT[n*232 + tt] = (tt < 196) ? vu[((size_t)b*TT + t0 + tt)*64 + n] : (ushort)0;
  }
  for (int idx = t; idx < 7168; idx += 256){
    int tt = idx >> 5, m = idx & 31;
    kpT[m*232 + tt] = (tt < 196) ? ku[((size_t)b*TT + t0 + tt)*32 + m] : (ushort)0;
  }
  __syncthreads();

  f32x4 accp[2];
  accp[0] = (f32x4){0.f,0.f,0.f,0.f};
  accp[1] = (f32x4){0.f,0.f,0.f,0.f};
  for (int ks=0; ks<7; ++ks){
    bf16x8 a = *(const bf16x8*)&vT[(w*16+l15)*232 + ks*32 + hi*8];
    #pragma unroll
    for (int nt=0; nt<2; ++nt){
      bf16x8 bv = *(const bf16x8*)&kpT[(nt*16+l15)*232 + ks*32 + hi*8];
      accp[nt] = __builtin_amdgcn_mfma_f32_16x16x32_bf16(a, bv, accp[nt], 0, 0, 0);
    }
  }
  #pragma unroll
  for (int nt=0;nt<2;++nt){
    #pragma unroll
    for (int r=0;r<4;++r){
      int row = w*16 + hi*4 + r;
      int col = nt*16 + l15;
      part[(((size_t)g*BB + b)*64 + row)*MM + col] = accp[nt][r];
    }
  }
  {
    int m = t & 31, h8 = t >> 5;
    float s = 0.f;
    int lo = h8*25, hic = lo+25 < 196 ? lo+25 : 196;
    for (int tt = lo; tt < hic; ++tt) s += bf2f(kpT[m*232 + tt]);
    ksh[h8][m] = s;
  }
  __syncthreads();
  if (t < 32){
    float s = 0.f;
    #pragma unroll
    for (int j=0;j<8;++j) s += ksh[j][t];
    kpsum_part[(size_t)g*1024 + b*32 + t] = s;
  }
}

// reduce partials -> kptvb (bf16) + kpsum (f32)
__global__ __launch_bounds__(256) void k_kptv_red(
    const float* __restrict__ part, const float* __restrict__ kpsum_part,
    __hip_bfloat16* __restrict__ kptvb, float* __restrict__ kpsum)
{
  const int t = threadIdx.x;
  const int idx = blockIdx.x*256 + t;
  float a = 0.f;
  #pragma unroll
  for (int g=0; g<16; ++g) a += part[(size_t)g*65536 + idx];
  kptvb[idx] = __float2bfloat16(a);
  if (blockIdx.x < 4){
    int kidx = blockIdx.x*256 + t;
    float s = 0.f;
    #pragma unroll
    for (int g=0; g<16; ++g) s += kpsum_part[(size_t)g*1024 + kidx];
    kpsum[kidx] = s;
  }
}

// ---------------- fused attention + proj + residuals + LN2 + MLP -> out; 64 pos/block
__global__ __launch_bounds__(256) void k_attn_mlp(
    const __hip_bfloat16* __restrict__ v_g, const __hip_bfloat16* __restrict__ qp,
    const float* __restrict__ kpsum, const __hip_bfloat16* __restrict__ kptvb,
    const __hip_bfloat16* __restrict__ wpjb, const float* __restrict__ projb,
    const __hip_bfloat16* __restrict__ convXb,
    const float* __restrict__ ln2_g, const float* __restrict__ ln2_b,
    const __hip_bfloat16* __restrict__ wm1b, const float* __restrict__ b1,
    const __hip_bfloat16* __restrict__ wm2b, const float* __restrict__ b2,
    float* __restrict__ out)
{
  __shared__ __align__(16) char smem[64512];
  ushort* qpb = (ushort*)smem;
  ushort* ktb = (ushort*)(smem + 5120);
  ushort* pjw = (ushort*)(smem + 10240);
  ushort* hb  = (ushort*)smem;
  ushort* t2  = (ushort*)(smem + 19456);
  ushort* w1b = (ushort*)(smem + 28672);
  ushort* w2b = (ushort*)(smem + 37888);
  float*  xosh= (float*)(smem + 47104);
  __shared__ float Ds[64];
  __shared__ float Dp[4][64];
  __shared__ float ks_s[32], pjb_s[64], b1_s[64], b2_s[64], g2_s[64], bb2_s[64];

  const int t = threadIdx.x;
  const int b = blockIdx.y;
  const int p0 = blockIdx.x*64;
  const int w = t>>6, lane = t&63, l15 = lane&15, hi = lane>>4;

  const ushort* qpu = (const ushort*)qp + ((size_t)b*TT + p0)*32;
  for (int idx = t; idx < 2048; idx += 256)
    qpb[(idx>>5)*40 + (idx&31)] = qpu[idx];
  const ushort* ktg = (const ushort*)kptvb + (size_t)b*2048;
  for (int idx = t; idx < 2048; idx += 256)
    ktb[(idx>>5)*40 + (idx&31)] = ktg[idx];
  const ushort* pju = (const ushort*)wpjb;
  const ushort* w1u = (const ushort*)wm1b;
  const ushort* w2u = (const ushort*)wm2b;
  for (int idx = t; idx < 4096; idx += 256){
    pjw[(idx>>6)*72 + (idx&63)] = pju[idx];
    w1b[(idx>>6)*72 + (idx&63)] = w1u[idx];
    w2b[(idx>>6)*72 + (idx&63)] = w2u[idx];
  }
  if (t < 32) ks_s[t] = kpsum[b*MM + t];
  if (t < 64){
    pjb_s[t] = projb[t]; b1_s[t] = b1[t]; b2_s[t] = b2[t];
    g2_s[t] = ln2_g[t];  bb2_s[t] = ln2_b[t];
  }
  __syncthreads();

  {
    int pos = t & 63, grp = t >> 6;
    float s = 0.f;
    #pragma unroll
    for (int j=0;j<8;++j){
      int m = grp*8 + j;
      s += bf2f(qpb[pos*40 + m]) * ks_s[m];
    }
    Dp[grp][pos] = s;
  }
  __syncthreads();
  if (t < 64) Ds[t] = Dp[0][t]+Dp[1][t]+Dp[2][t]+Dp[3][t] + 1e-8f;
  __syncthreads();

  f32x4 acc1[4];
  #pragma unroll
  for (int nb=0;nb<4;++nb) acc1[nb] = (f32x4){0.f,0.f,0.f,0.f};
  {
    bf16x8 a = *(const bf16x8*)&qpb[(w*16 + l15)*40 + hi*8];
    #pragma unroll
    for (int nb=0;nb<4;++nb){
      bf16x8 bv = *(const bf16x8*)&ktb[(nb*16 + l15)*40 + hi*8];
      acc1[nb] = __builtin_amdgcn_mfma_f32_16x16x32_bf16(a, bv, acc1[nb], 0, 0, 0);
    }
  }
  #pragma unroll
  for (int nb=0;nb<4;++nb){
    #pragma unroll
    for (int r=0;r<4;++r){
      int row = w*16 + hi*4 + r;
      t2[row*72 + nb*16 + l15] = bfbits(acc1[nb][r] / Ds[row]);
    }
  }
  __syncthreads();

  f32x4 acc2[4];
  #pragma unroll
  for (int nb=0;nb<4;++nb) acc2[nb] = (f32x4){0.f,0.f,0.f,0.f};
  #pragma unroll
  for (int ks=0; ks<2; ++ks){
    bf16x8 a2 = *(const bf16x8*)&t2[(w*16 + l15)*72 + ks*32 + hi*8];
    #pragma unroll
    for (int nb=0;nb<4;++nb){
      bf16x8 bv2 = *(const bf16x8*)&pjw[(nb*16 + l15)*72 + ks*32 + hi*8];
      acc2[nb] = __builtin_amdgcn_mfma_f32_16x16x32_bf16(a2, bv2, acc2[nb], 0, 0, 0);
    }
  }
  const ushort* cxu = (const ushort*)convXb;
  const ushort* vu  = (const ushort*)v_g;
  #pragma unroll
  for (int nb=0;nb<4;++nb){
    #pragma unroll
    for (int r=0;r<4;++r){
      int row = w*16 + hi*4 + r;
      int col = nb*16 + l15;
      const size_t off = ((size_t)b*TT + p0 + row)*64 + col;
      xosh[row*68 + col] = bf2f(vu[off]) + acc2[nb][r] + pjb_s[col] + bf2f(cxu[off]);
    }
  }
  __syncthreads();

  // LN2 (width-64 xor-shuffle) -> t2 (bf16)
  {
    const int n = t & 63, p = t >> 6;
    const float g2 = g2_s[n], bb2 = bb2_s[n];
    for (int sp=0; sp<16; ++sp){
      const int pos = sp*4 + p;
      const float xv = xosh[pos*68 + n];
      float s1 = xv, s2 = xv*xv;
      #pragma unroll
      for (int o=32;o;o>>=1){
        s1 += __shfl_xor(s1, o, 64);
        s2 += __shfl_xor(s2, o, 64);
      }
      float mu = s1*(1.f/64.f);
      float rs = rsqrtf(s2*(1.f/64.f) - mu*mu + 1e-5f);
      t2[pos*72 + n] = bfbits((xv - mu)*rs*g2 + bb2);
    }
  }
  __syncthreads();

  f32x4 acc3[4];
  #pragma unroll
  for (int nb=0;nb<4;++nb) acc3[nb] = (f32x4){0.f,0.f,0.f,0.f};
  #pragma unroll
  for (int ks=0; ks<2; ++ks){
    bf16x8 a3 = *(const bf16x8*)&t2[(w*16 + l15)*72 + ks*32 + hi*8];
    #pragma unroll
    for (int nb=0;nb<4;++nb){
      bf16x8 bv3 = *(const bf16x8*)&w1b[(nb*16 + l15)*72 + ks*32 + hi*8];
      acc3[nb] = __builtin_amdgcn_mfma_f32_16x16x32_bf16(a3, bv3, acc3[nb], 0, 0, 0);
    }
  }
  __syncthreads();
  #pragma unroll
  for (int nb=0;nb<4;++nb){
    #pragma unroll
    for (int r=0;r<4;++r){
      int row = w*16 + hi*4 + r;
      int col = nb*16 + l15;
      hb[row*72 + col] = bfbits(geluf(acc3[nb][r] + b1_s[col]));
    }
  }
  __syncthreads();

  f32x4 acc4[4];
  #pragma unroll
  for (int nb=0;nb<4;++nb) acc4[nb] = (f32x4){0.f,0.f,0.f,0.f};
  #pragma unroll
  for (int ks=0; ks<2; ++ks){
    bf16x8 a4 = *(const bf16x8*)&hb[(w*16 + l15)*72 + ks*32 + hi*8];
    #pragma unroll
    for (int nb=0;nb<4;++nb){
      bf16x8 bv4 = *(const bf16x8*)&w2b[(nb*16 + l15)*72 + ks*32 + hi*8];
      acc4[nb] = __builtin_amdgcn_mfma_f32_16x16x32_bf16(a4, bv4, acc4[nb], 0, 0, 0);
    }
  }
  #pragma unroll
  for (int nb=0;nb<4;++nb){
    #pragma unroll
    for (int r=0;r<4;++r){
      int row = w*16 + hi*4 + r;
      int col = nb*16 + l15;
      const size_t off = ((size_t)b*TT + p0 + row)*64 + col;
      out[off] = xosh[row*68 + col] + acc4[nb][r] + b2_s[col];
    }
  }
}

extern "C" void kernel_launch(void* const* d_in, const int* in_sizes, int n_in,
                              void* d_out, int out_size, void* d_ws, size_t ws_size,
                              hipStream_t stream)
{
  const float* x      = (const float*)d_in[0];
  const float* prm_w  = (const float*)d_in[1];
  const float* prm_b  = (const float*)d_in[2];
  const float* pcm_w1 = (const float*)d_in[3];
  const float* pcm_b1 = (const float*)d_in[4];
  const float* pcm_w2 = (const float*)d_in[5];
  const float* pcm_b2 = (const float*)d_in[6];
  const float* bn_g   = (const float*)d_in[7];
  const float* bn_b   = (const float*)d_in[8];
  const float* bn_mean= (const float*)d_in[9];
  const float* bn_var = (const float*)d_in[10];
  const float* pcm_w3 = (const float*)d_in[11];
  const float* pcm_b3 = (const float*)d_in[12];
  const float* ln1_g  = (const float*)d_in[13];
  const float* ln1_b  = (const float*)d_in[14];
  const float* kqv_w  = (const float*)d_in[15];
  const float* kqv_b  = (const float*)d_in[16];
  const float* w_perf = (const float*)d_in[17];
  const float* proj_w = (const float*)d_in[18];
  const float* proj_b = (const float*)d_in[19];
  const float* ln2_g  = (const float*)d_in[20];
  const float* ln2_b  = (const float*)d_in[21];
  const float* mlp_w1 = (const float*)d_in[22];
  const float* mlp_b1 = (const float*)d_in[23];
  const float* mlp_w2 = (const float*)d_in[24];
  const float* mlp_b2 = (const float*)d_in[25];

  float* ws = (float*)d_ws;
  __hip_bfloat16* convXb = (__hip_bfloat16*)(ws + OFF_CONVX);
  __hip_bfloat16* c2b = (__hip_bfloat16*)(ws + OFF_C2B);
  __hip_bfloat16* xn  = (__hip_bfloat16*)(ws + OFF_XN);
  __hip_bfloat16* c1b = (__hip_bfloat16*)(ws + OFF_C1B);
  __hip_bfloat16* v_g = (__hip_bfloat16*)(ws + OFF_V);
  __hip_bfloat16* kp  = (__hip_bfloat16*)(ws + OFF_KP);
  __hip_bfloat16* qp  = (__hip_bfloat16*)(ws + OFF_QP);
  float* part  = ws + OFF_PART;
  __hip_bfloat16* kptvb = (__hip_bfloat16*)(ws + OFF_KPTV);
  float* kpsum_part = ws + OFF_KPSP;
  float* kpsum = ws + OFF_KPSUM;
  float* wpt   = ws + OFF_WPT;
  __hip_bfloat16* wkb  = (__hip_bfloat16*)(ws + OFF_WKB);
  __hip_bfloat16* wc2b = (__hip_bfloat16*)(ws + OFF_WC2B);
  __hip_bfloat16* wt3b = (__hip_bfloat16*)(ws + OFF_WT3B);
  __hip_bfloat16* wc1b = (__hip_bfloat16*)(ws + OFF_WC1B);
  __hip_bfloat16* wpjb = (__hip_bfloat16*)(ws + OFF_WPJB);
  __hip_bfloat16* wm1b = (__hip_bfloat16*)(ws + OFF_WM1B);
  __hip_bfloat16* wm2b = (__hip_bfloat16*)(ws + OFF_WM2B);
  __hip_bfloat16* wpfh = (__hip_bfloat16*)(ws + OFF_WPFH);
  __hip_bfloat16* wpfl = (__hip_bfloat16*)(ws + OFF_WPFL);
  float* out   = (float*)d_out;

  k_wtrans<<<dim3(699), 256, 0, stream>>>(prm_w, kqv_w, pcm_w2, pcm_w3, pcm_w1,
                                          proj_w, mlp_w1, mlp_w2, w_perf,
                                          wpt, wkb, wc2b, wt3b, wc1b,
                                          wpjb, wm1b, wm2b, wpfh, wpfl);
  // FUSED prm_ln (VALU) + conv1 (MFMA): 896 groups x (8 prm + 7 conv1)
  k_prm_conv1<<<dim3(13440), 256, 0, stream>>>(x, wpt, prm_b, ln1_g, ln1_b, xn,
                                               wc1b, pcm_b1, c1b);
  // stem rest (MFMA)
  k_conv2<<<dim3(49,BB), 256, 0, stream>>>(c1b, wc2b, pcm_b2, bn_g, bn_b,
                                           bn_mean, bn_var, c2b);
  k_conv3<<<dim3(49,BB), 256, 0, stream>>>(c2b, wt3b, pcm_b3, convXb);
  // KQV GEMM (MFMA) + Performer features (MFMA split dots)
  k_kqv_perf<<<dim3(1568), 256, 0, stream>>>(xn, wkb, kqv_b, wpfh, wpfl, v_g, kp, qp);
  // Performer reductions (MFMA)
  k_kptv<<<dim3(16,BB), 256, 0, stream>>>(v_g, kp, part, kpsum_part);
  k_kptv_red<<<dim3(256), 256, 0, stream>>>(part, kpsum_part, kptvb, kpsum);
  // fused attention + MLP -> out
  k_attn_mlp<<<dim3(49,BB), 256, 0, stream>>>(v_g, qp, kpsum, kptvb, wpjb, proj_b,
                                              convXb, ln2_g, ln2_b, wm1b, mlp_b1,
                                              wm2b, mlp_b2, out);
}

// Round 19
// 467.699 us; speedup vs baseline: 1.0644x; 1.0644x over previous
//
#include <hip/hip_runtime.h>
#include <hip/hip_bf16.h>
#include <cstddef>

// Problem constants
#define BB    32
#define IMG   224
#define CIN   3
#define ED    64
#define TD    64
#define MM    32
#define HP    56
#define TT    3136      // 56*56
#define C4    256       // 4*ED
#define KQVN  192       // 3*TD

typedef __attribute__((ext_vector_type(8))) short bf16x8;
typedef __attribute__((ext_vector_type(4))) float f32x4;

// workspace offsets (float units). v/kp/qp bf16. (R17-fixed layout)
#define OFF_CONVX  0u           // convXb bf16: [0, 3,211,264) f
#define OFF_C2B    3211264u     // c2b bf16: [3.21M, 6.42M) f
#define OFF_XN     6422528u     // 12,845,056 f (25,690,112 bf16)
#define OFF_C1B    19267584u    // bf16; dead after conv2, then v/kp/qp overwrite
#define OFF_V      19267584u    // bf16
#define OFF_KP     25690112u    // bf16
#define OFF_QP     28901376u    // bf16
#define OFF_PART   32112640u    // 1,048,576 f
#define OFF_KPTV   33161216u    // region 65,536 f
#define OFF_KPSP   (OFF_KPTV + 32768u)
#define OFF_WPJB   (OFF_KPTV + 49152u)
#define OFF_WM1B   (OFF_KPTV + 51200u)
#define OFF_WM2B   (OFF_KPTV + 53248u)
#define OFF_WPFH   (OFF_KPTV + 55296u)
#define OFF_WPFL   (OFF_KPTV + 56320u)
#define OFF_KPSUM  33226752u    // 1,024 f
// weights aliased into PART region (dead once k_kptv writes part)
#define OFF_WPT    (OFF_PART)             // 37,632 f
#define OFF_WKB    (OFF_PART + 37632u)    // 24,576 f
#define OFF_WC2B   (OFF_PART + 62208u)    // 18,432 f
#define OFF_WT3B   (OFF_PART + 80640u)    // 18,432 f
#define OFF_WC1B   (OFF_PART + 99072u)    // 1,024 f
// total 33,227,776 f = 132.9 MB

__device__ __forceinline__ float geluf(float v){
  return 0.5f*v*(1.f + erff(v*0.70710678118654752f));
}
__device__ __forceinline__ float siluf(float v){
  return v/(1.f + expf(-v));
}
__device__ __forceinline__ ushort bfbits(float v){
  __hip_bfloat16 h = __float2bfloat16(v);
  return *reinterpret_cast<ushort*>(&h);
}
__device__ __forceinline__ float bf2f(ushort u){
  return __uint_as_float(((unsigned)u) << 16);
}

// ---------------- weight transposes / casts
__global__ __launch_bounds__(256) void k_wtrans(
    const float* __restrict__ prm_w, const float* __restrict__ kqv_w,
    const float* __restrict__ pcm_w2, const float* __restrict__ pcm_w3,
    const float* __restrict__ pcm_w1, const float* __restrict__ proj_w,
    const float* __restrict__ mlp_w1, const float* __restrict__ mlp_w2,
    const float* __restrict__ wperf,
    float* __restrict__ wpt, __hip_bfloat16* __restrict__ wkb,
    __hip_bfloat16* __restrict__ wc2b, __hip_bfloat16* __restrict__ wt3b,
    __hip_bfloat16* __restrict__ wc1b, __hip_bfloat16* __restrict__ wpjb,
    __hip_bfloat16* __restrict__ wm1b, __hip_bfloat16* __restrict__ wm2b,
    __hip_bfloat16* __restrict__ wpfh, __hip_bfloat16* __restrict__ wpfl)
{
  int idx = blockIdx.x*256 + threadIdx.x;
  if (idx < 37632){
    int oc = idx & 63, r = idx >> 6;        // r = i*147+tap
    int i = r/147, tap = r - i*147;
    wpt[idx] = prm_w[(i*64 + oc)*147 + tap];
  } else if (idx < 86784){
    int i4 = idx - 37632;
    wkb[i4] = __float2bfloat16(kqv_w[i4]);
  } else if (idx < 123648){
    int i2 = idx - 86784;                   // wc2b[oc][ (kh*3+kw)*64+ci ]
    int oc = i2/576, rem = i2 - oc*576;
    int khkw = rem >> 6, ci = rem & 63;
    int kh = khkw/3, kw = khkw - kh*3;
    wc2b[i2] = __float2bfloat16(pcm_w2[(oc*64+ci)*9 + kh*3 + kw]);
  } else if (idx < 160512){
    int i3 = idx - 123648;
    int oc = i3/576, rem = i3 - oc*576;
    int khkw = rem >> 6, ci = rem & 63;
    int kh = khkw/3, kw = khkw - kh*3;
    wt3b[i3] = __float2bfloat16(pcm_w3[(oc*64+ci)*9 + kh*3 + kw]);
  } else if (idx < 162560){
    int i5 = idx - 160512;                  // wc1b[oc][k], k pad32
    int oc = i5 >> 5, k = i5 & 31;
    float v = 0.f;
    if (k < 27) v = pcm_w1[oc*27 + k];
    wc1b[i5] = __float2bfloat16(v);
  } else if (idx < 166656){
    wpjb[idx - 162560] = __float2bfloat16(proj_w[idx - 162560]);
  } else if (idx < 170752){
    wm1b[idx - 166656] = __float2bfloat16(mlp_w1[idx - 166656]);
  } else if (idx < 174848){
    wm2b[idx - 170752] = __float2bfloat16(mlp_w2[idx - 170752]);
  } else if (idx < 176896){
    int i6 = idx - 174848;                  // wperf hi [m][c]
    wpfh[i6] = __float2bfloat16(wperf[i6]);
  } else if (idx < 178944){
    int i7 = idx - 176896;                  // wperf lo residual
    float v = wperf[i7];
    float h = bf2f(bfbits(v));
    wpfl[i7] = __float2bfloat16(v - h);
  }
}

// ---------------- conv1 (MFMA implicit GEMM): x -> c1b NHWC bf16, 3x3 s2 p1, SiLU
__global__ __launch_bounds__(256) void k_conv1(
    const float* __restrict__ x, const __hip_bfloat16* __restrict__ wc1b,
    const float* __restrict__ bias, __hip_bfloat16* __restrict__ c1b)
{
  __shared__ __align__(16) ushort xs[3*17*18];
  __shared__ __align__(16) ushort As[64*40];
  const int t = threadIdx.x;
  const int b = blockIdx.y;
  const int th = blockIdx.x/14, tw = blockIdx.x - th*14;
  const int oh0 = th*8, ow0 = tw*8;
  const int ih0 = oh0*2 - 1, iw0 = ow0*2 - 1;
  const int w = t>>6, lane = t&63, l15 = lane&15, hi = lane>>4;

  const float* xb = x + (size_t)b*CIN*IMG*IMG;
  for (int idx = t; idx < 918; idx += 256){
    int ci = idx/306, rem = idx - ci*306;
    int r = rem/18, c = rem - r*18;
    float v = 0.f;
    int ih = ih0 + r, iw = iw0 + c;
    if (c < 17 && (unsigned)ih < 224u && (unsigned)iw < 224u)
      v = xb[(ci*IMG+ih)*IMG+iw];
    xs[idx] = bfbits(v);
  }
  __syncthreads();
  for (int idx = t; idx < 2048; idx += 256){
    int pos = idx >> 5, k = idx & 31;
    ushort v = 0;
    if (k < 27){
      int ci = k/9, rem = k - ci*9;
      int kh = rem/3, kw = rem - kh*3;
      v = xs[(ci*17 + (pos>>3)*2 + kh)*18 + (pos&7)*2 + kw];
    }
    As[pos*40 + k] = v;
  }
  __syncthreads();

  float bs4[4];
  #pragma unroll
  for (int nb=0;nb<4;++nb) bs4[nb] = bias[nb*16+l15];
  f32x4 acc[4];
  #pragma unroll
  for (int nb=0;nb<4;++nb) acc[nb] = (f32x4){0.f,0.f,0.f,0.f};
  const ushort* wq = (const ushort*)wc1b;
  {
    bf16x8 a = *(const bf16x8*)&As[(w*16+l15)*40 + hi*8];
    #pragma unroll
    for (int nb=0;nb<4;++nb){
      bf16x8 bv = *(const bf16x8*)&wq[(nb*16+l15)*32 + hi*8];
      acc[nb] = __builtin_amdgcn_mfma_f32_16x16x32_bf16(a, bv, acc[nb], 0, 0, 0);
    }
  }
  #pragma unroll
  for (int nb=0;nb<4;++nb){
    #pragma unroll
    for (int r=0;r<4;++r){
      int row = w*16 + hi*4 + r;
      int oh = oh0 + (row>>3), ow = ow0 + (row&7);
      c1b[(((size_t)b*112+oh)*112+ow)*64 + nb*16+l15] =
        __float2bfloat16(siluf(acc[nb][r] + bs4[nb]));
    }
  }
}

// ---------------- PRM conv core: phase-major layout, wave-uniform broadcast reads.
#define LOADX(PH) do{ const float4* xr_ = (const float4*)(rowb + (PH)*20); \
  *(float4*)&X[0]=xr_[0]; *(float4*)&X[4]=xr_[1]; *(float4*)&X[8]=xr_[2]; \
  *(float4*)&X[12]=xr_[3]; *(float4*)&X[16]=xr_[4]; }while(0)
#define TAP(KW,Q0) do{ const float wv_ = wrow[(KW)*64]; \
  v[0]+=wv_*X[(Q0)+0];  v[1]+=wv_*X[(Q0)+1];  v[2]+=wv_*X[(Q0)+2];  v[3]+=wv_*X[(Q0)+3]; \
  v[4]+=wv_*X[(Q0)+4];  v[5]+=wv_*X[(Q0)+5];  v[6]+=wv_*X[(Q0)+6];  v[7]+=wv_*X[(Q0)+7]; \
  v[8]+=wv_*X[(Q0)+8];  v[9]+=wv_*X[(Q0)+9];  v[10]+=wv_*X[(Q0)+10]; v[11]+=wv_*X[(Q0)+11]; \
  v[12]+=wv_*X[(Q0)+12]; v[13]+=wv_*X[(Q0)+13]; }while(0)

template<int D>
__device__ __forceinline__ void prm_core(const float* __restrict__ xt2,
    const float* __restrict__ wq, float v[14])
{
  constexpr int R0 = 12 - 3*D;
  #pragma unroll 1
  for (int ci=0; ci<3; ++ci){
    #pragma unroll 1
    for (int kh=0; kh<7; ++kh){
      const float* rowb = xt2 + ci*2000 + (R0 + kh*D)*80;
      const float* wrow = wq + ((ci*7+kh)*7)*64;
      float X[20];
      if constexpr (D == 1){
        LOADX(0); TAP(3,3);
        LOADX(1); TAP(0,2); TAP(4,3);
        LOADX(2); TAP(1,2); TAP(5,3);
        LOADX(3); TAP(2,2); TAP(6,3);
      } else if constexpr (D == 2){
        LOADX(0); TAP(1,2); TAP(3,3); TAP(5,4);
        LOADX(2); TAP(0,1); TAP(2,2); TAP(4,3); TAP(6,4);
      } else if constexpr (D == 3){
        LOADX(0); TAP(3,3);
        LOADX(1); TAP(2,2); TAP(6,5);
        LOADX(2); TAP(1,1); TAP(5,4);
        LOADX(3); TAP(0,0); TAP(4,3);
      } else {
        LOADX(0); TAP(0,0); TAP(1,1); TAP(2,2); TAP(3,3); TAP(4,4); TAP(5,5); TAP(6,6);
      }
    }
  }
}

// ---------------- PRM convs + GELU + LN -> xn (bf16). one block = 14-wide strip
__global__ __launch_bounds__(256) void k_prm_ln(
    const float* __restrict__ x, const float* __restrict__ wpt,
    const float* __restrict__ prm_b, const float* __restrict__ ln_g,
    const float* __restrict__ ln_b, __hip_bfloat16* __restrict__ xn)
{
  __shared__ __align__(16) float xt2[6000];   // [3][25][4][20] phase-major
  __shared__ float wred[4][14][2];
  const int t = threadIdx.x;
  const int b = blockIdx.y;
  const int oh  = blockIdx.x >> 2;
  const int owt = blockIdx.x & 3;
  const int ow0 = owt*14;
  const int ih0 = oh*4 - 11;
  const int iw0 = ow0*4 - 11;

  const float* xb = x + (size_t)b*CIN*IMG*IMG;
  for (int idx = t; idx < 6000; idx += 256){
    int ci  = idx / 2000;
    int rem = idx - ci*2000;
    int r   = rem / 80;
    int cc  = rem - r*80;
    int ih = ih0 + r, iw = iw0 + cc;
    float val = 0.f;
    if ((unsigned)ih < (unsigned)IMG && (unsigned)iw < (unsigned)IMG)
      val = xb[(ci*IMG+ih)*IMG+iw];
    xt2[(ci*25 + r)*80 + (cc&3)*20 + (cc>>2)] = val;
  }
  __syncthreads();

  const int i = t >> 6, lane = t & 63;
  float v[14];
  const float bi = prm_b[i*64+lane];
  #pragma unroll
  for (int p=0;p<14;++p) v[p] = bi;
  const float* wq = wpt + (i*147)*64 + lane;   // [tap][oc] coalesced

  if      (i == 0) prm_core<1>(xt2, wq, v);
  else if (i == 1) prm_core<2>(xt2, wq, v);
  else if (i == 2) prm_core<3>(xt2, wq, v);
  else             prm_core<4>(xt2, wq, v);

  // GELU + per-wave LN partials via shuffles
  #pragma unroll
  for (int p=0;p<14;++p) v[p] = geluf(v[p]);
  #pragma unroll
  for (int p=0;p<14;++p){
    float s1 = v[p], s2 = v[p]*v[p];
    #pragma unroll
    for (int o=32;o;o>>=1){
      s1 += __shfl_xor(s1, o, 64);
      s2 += __shfl_xor(s2, o, 64);
    }
    if (lane == 0){ wred[i][p][0] = s1; wred[i][p][1] = s2; }
  }
  __syncthreads();
  const float lg = ln_g[t], lb = ln_b[t];
  const int s_base = oh*HP + ow0;
  #pragma unroll
  for (int p=0;p<14;++p){
    float S1 = wred[0][p][0]+wred[1][p][0]+wred[2][p][0]+wred[3][p][0];
    float S2 = wred[0][p][1]+wred[1][p][1]+wred[2][p][1]+wred[3][p][1];
    float mu = S1*(1.f/256.f);
    float rs = rsqrtf(S2*(1.f/256.f) - mu*mu + 1e-5f);
    float outv = (v[p]-mu)*rs*lg + lb;
    xn[((size_t)(b*TT + s_base + p))*256 + t] = __float2bfloat16(outv);
  }
}

// ---------------- conv2 (MFMA implicit GEMM): c1b -> c2b NHWC bf16, 3x3 s2 p1, BN+SiLU
__global__ __launch_bounds__(256) void k_conv2(
    const __hip_bfloat16* __restrict__ c1b, const __hip_bfloat16* __restrict__ wc2b,
    const float* __restrict__ bias, const float* __restrict__ g,
    const float* __restrict__ bb, const float* __restrict__ mean,
    const float* __restrict__ var, __hip_bfloat16* __restrict__ c2b)
{
  __shared__ __align__(16) ushort xs[17*17*72];
  const int b = blockIdx.y;
  const int th = blockIdx.x/7, tw = blockIdx.x - th*7;
  const int oh0 = th*8, ow0 = tw*8;
  const int t = threadIdx.x;
  const int w = t>>6, lane = t&63, l15 = lane&15, hi = lane>>4;

  const int ih0 = oh0*2-1, iw0 = ow0*2-1;
  const ushort* c1u = (const ushort*)c1b;
  for (int seg = t; seg < 2312; seg += 256){
    int pos = seg >> 3, s8 = seg & 7;
    int r = pos/17, c = pos - r*17;
    int ih = ih0 + r, iw = iw0 + c;
    uint4 val = {0,0,0,0};
    if ((unsigned)ih < 112u && (unsigned)iw < 112u)
      val = *(const uint4*)&c1u[(((size_t)b*112+ih)*112+iw)*64 + s8*8];
    *(uint4*)&xs[(r*17+c)*72 + s8*8] = val;
  }
  __syncthreads();

  float bs4[4], iv4[4], mn4[4], bo4[4];
  #pragma unroll
  for (int nb=0;nb<4;++nb){
    int oc = nb*16+l15;
    bs4[nb] = bias[oc];
    iv4[nb] = g[oc]*rsqrtf(var[oc]+1e-5f);
    mn4[nb] = mean[oc];
    bo4[nb] = bb[oc];
  }

  f32x4 acc[4];
  #pragma unroll
  for (int nb=0;nb<4;++nb) acc[nb] = (f32x4){0.f,0.f,0.f,0.f};

  const int p = w*16 + l15, pr = p>>3, pc = p&7;
  const ushort* wq = (const ushort*)wc2b;

  for (int ks=0; ks<18; ++ks){
    const int k0 = ks*32 + hi*8;
    const int khkw = k0 >> 6, ci0 = k0 & 63;
    const int kh = khkw/3, kw = khkw - kh*3;
    bf16x8 a = *(const bf16x8*)&xs[((2*pr+kh)*17 + 2*pc+kw)*72 + ci0];
    #pragma unroll
    for (int nb=0;nb<4;++nb){
      bf16x8 bv = *(const bf16x8*)&wq[(nb*16+l15)*576 + k0];
      acc[nb] = __builtin_amdgcn_mfma_f32_16x16x32_bf16(a, bv, acc[nb], 0, 0, 0);
    }
  }

  #pragma unroll
  for (int nb=0;nb<4;++nb){
    #pragma unroll
    for (int r=0;r<4;++r){
      int pp = w*16 + hi*4 + r;
      int oh = oh0 + (pp>>3), ow = ow0 + (pp&7);
      float vv = acc[nb][r] + bs4[nb];
      vv = (vv - mn4[nb])*iv4[nb] + bo4[nb];
      c2b[(((size_t)b*56+oh)*56+ow)*64 + nb*16+l15] = __float2bfloat16(siluf(vv));
    }
  }
}

// ---------------- conv3 (MFMA implicit GEMM): c2b -> convXb (bf16 NHWC), 3x3 s1 p1, SiLU
__global__ __launch_bounds__(256) void k_conv3(
    const __hip_bfloat16* __restrict__ c2b, const __hip_bfloat16* __restrict__ wt3b,
    const float* __restrict__ bias, __hip_bfloat16* __restrict__ convXb)
{
  __shared__ __align__(16) ushort xs[10*12*72];
  const int b = blockIdx.y;
  const int th = blockIdx.x/7, tw = blockIdx.x - th*7;
  const int oh0 = th*8, ow0 = tw*8;
  const int t = threadIdx.x;
  const int w = t>>6, lane = t&63, l15 = lane&15, hi = lane>>4;

  const ushort* c2u = (const ushort*)c2b;
  for (int seg = t; seg < 960; seg += 256){
    int pos = seg >> 3, s8 = seg & 7;
    int r = pos/12, c = pos - r*12;
    int ih = oh0 - 1 + r, iw = ow0 - 1 + c;
    uint4 val = {0,0,0,0};
    if ((unsigned)ih < 56u && (unsigned)iw < 56u)
      val = *(const uint4*)&c2u[(((size_t)b*56+ih)*56+iw)*64 + s8*8];
    *(uint4*)&xs[(r*12+c)*72 + s8*8] = val;
  }
  __syncthreads();

  float bs4[4];
  #pragma unroll
  for (int nb=0;nb<4;++nb) bs4[nb] = bias[nb*16+l15];

  f32x4 acc[4];
  #pragma unroll
  for (int nb=0;nb<4;++nb) acc[nb] = (f32x4){0.f,0.f,0.f,0.f};

  const int p = w*16 + l15, pr = p>>3, pc = p&7;
  const ushort* wq = (const ushort*)wt3b;

  for (int ks=0; ks<18; ++ks){
    const int k0 = ks*32 + hi*8;
    const int khkw = k0 >> 6, ci0 = k0 & 63;
    const int kh = khkw/3, kw = khkw - kh*3;
    bf16x8 a = *(const bf16x8*)&xs[((pr+kh)*12 + pc+kw)*72 + ci0];
    #pragma unroll
    for (int nb=0;nb<4;++nb){
      bf16x8 bv = *(const bf16x8*)&wq[(nb*16+l15)*576 + k0];
      acc[nb] = __builtin_amdgcn_mfma_f32_16x16x32_bf16(a, bv, acc[nb], 0, 0, 0);
    }
  }

  #pragma unroll
  for (int nb=0;nb<4;++nb){
    #pragma unroll
    for (int r=0;r<4;++r){
      int pp = w*16 + hi*4 + r;
      int oh = oh0 + (pp>>3), ow = ow0 + (pp&7);
      int s = oh*HP + ow;
      convXb[((size_t)b*TT + s)*64 + nb*16+l15] =
        __float2bfloat16(siluf(acc[nb][r] + bs4[nb]));
    }
  }
}

// ---------------- KQV GEMM (bf16 MFMA) + Performer feature map (bf16-split MFMA dots)
__global__ __launch_bounds__(256) void k_kqv_perf(
    const __hip_bfloat16* __restrict__ xn, const __hip_bfloat16* __restrict__ wkb,
    const float* __restrict__ kqv_b,
    const __hip_bfloat16* __restrict__ wpfh, const __hip_bfloat16* __restrict__ wpfl,
    __hip_bfloat16* __restrict__ v_g, __hip_bfloat16* __restrict__ kp,
    __hip_bfloat16* __restrict__ qp)
{
  __shared__ __align__(16) char smem[36864];
  __shared__ __align__(16) ushort wph[32*72];
  __shared__ __align__(16) ushort wpl[32*72];
  __shared__ float kqvb_s[192];
  __shared__ float xd_s[128];
  ushort* As  = (ushort*)smem;
  ushort* Bs  = (ushort*)(smem + 9216);
  ushort* zhb = (ushort*)smem;
  ushort* zlb = (ushort*)(smem + 18432);

  const int t = threadIdx.x;
  const int m0 = blockIdx.x*64;
  const int w = t >> 6, lane = t & 63;
  const int l15 = lane & 15, hi = lane >> 4;

  const ushort* wph_g = (const ushort*)wpfh;
  const ushort* wpl_g = (const ushort*)wpfl;
  for (int idx = t; idx < 2048; idx += 256){
    int row = idx >> 6, c = idx & 63;
    wph[row*72 + c] = wph_g[idx];
    wpl[row*72 + c] = wpl_g[idx];
  }
  if (t < 192) kqvb_s[t] = kqv_b[t];

  f32x4 acc[12];
  #pragma unroll
  for (int nb=0;nb<12;++nb) acc[nb] = (f32x4){0.f,0.f,0.f,0.f};

  const ushort* xnu = (const ushort*)xn;
  const ushort* wku = (const ushort*)wkb;

  for (int kc=0; kc<4; ++kc){
    #pragma unroll
    for (int ss=0; ss<2; ++ss){
      int seg = ss*256 + t;
      int row = seg >> 3, c8 = seg & 7;
      *(uint4*)&As[row*72 + c8*8] =
        *(const uint4*)&xnu[((size_t)(m0+row))*256 + kc*64 + c8*8];
    }
    #pragma unroll
    for (int ss=0; ss<6; ++ss){
      int seg = ss*256 + t;
      int row = seg >> 3, c8 = seg & 7;
      *(uint4*)&Bs[row*72 + c8*8] =
        *(const uint4*)&wku[row*256 + kc*64 + c8*8];
    }
    __syncthreads();
    #pragma unroll
    for (int ks=0; ks<2; ++ks){
      bf16x8 a = *(const bf16x8*)&As[(16*w + l15)*72 + ks*32 + hi*8];
      #pragma unroll
      for (int nb=0;nb<12;++nb){
        bf16x8 bv = *(const bf16x8*)&Bs[(nb*16 + l15)*72 + ks*32 + hi*8];
        acc[nb] = __builtin_amdgcn_mfma_f32_16x16x32_bf16(a, bv, acc[nb], 0, 0, 0);
      }
    }
    __syncthreads();
  }

  // scatter: k,q -> zhb/zlb (bf16 split); v -> global bf16 (+bias)
  #pragma unroll
  for (int nb=0;nb<12;++nb){
    int col = nb*16 + l15;
    float bias = kqvb_s[col];
    #pragma unroll
    for (int r=0;r<4;++r){
      int row = w*16 + hi*4 + r;
      float val = acc[nb][r] + bias;
      if (col < 128){
        int zrow = (col >> 6)*64 + row;
        int zc = col & 63;
        ushort zh = bfbits(val);
        zhb[zrow*72 + zc] = zh;
        zlb[zrow*72 + zc] = bfbits(val - bf2f(zh));
      } else {
        ((ushort*)v_g)[((size_t)(m0+row))*64 + (col-128)] = bfbits(val);
      }
    }
  }
  __syncthreads();

  if (t < 128){
    float s = 0.f;
    #pragma unroll
    for (int c8=0;c8<8;++c8){
      bf16x8 zh8 = *(const bf16x8*)&zhb[t*72 + c8*8];
      bf16x8 zl8 = *(const bf16x8*)&zlb[t*72 + c8*8];
      #pragma unroll
      for (int j=0;j<8;++j){
        float z = bf2f((ushort)zh8[j]) + bf2f((ushort)zl8[j]);
        s += z*z;
      }
    }
    xd_s[t] = 0.5f*s;
  }
  __syncthreads();

  // dots MFMA: M=128, N=32, K=64; wh*zh + wh*zl + wl*zh
  f32x4 accd[2][2];
  #pragma unroll
  for (int ri=0;ri<2;++ri)
    #pragma unroll
    for (int nb=0;nb<2;++nb) accd[ri][nb] = (f32x4){0.f,0.f,0.f,0.f};
  #pragma unroll
  for (int ri=0;ri<2;++ri){
    const int rb = 2*w + ri;
    #pragma unroll
    for (int ks=0;ks<2;++ks){
      bf16x8 ah = *(const bf16x8*)&zhb[(rb*16 + l15)*72 + ks*32 + hi*8];
      bf16x8 al = *(const bf16x8*)&zlb[(rb*16 + l15)*72 + ks*32 + hi*8];
      #pragma unroll
      for (int nb=0;nb<2;++nb){
        bf16x8 bh = *(const bf16x8*)&wph[(nb*16 + l15)*72 + ks*32 + hi*8];
        bf16x8 bl = *(const bf16x8*)&wpl[(nb*16 + l15)*72 + ks*32 + hi*8];
        accd[ri][nb] = __builtin_amdgcn_mfma_f32_16x16x32_bf16(ah, bh, accd[ri][nb], 0, 0, 0);
        accd[ri][nb] = __builtin_amdgcn_mfma_f32_16x16x32_bf16(al, bh, accd[ri][nb], 0, 0, 0);
        accd[ri][nb] = __builtin_amdgcn_mfma_f32_16x16x32_bf16(ah, bl, accd[ri][nb], 0, 0, 0);
      }
    }
  }
  #pragma unroll
  for (int ri=0;ri<2;++ri){
    const int rb = 2*w + ri;
    #pragma unroll
    for (int nb=0;nb<2;++nb){
      const int m = nb*16 + l15;
      #pragma unroll
      for (int r=0;r<4;++r){
        int row = rb*16 + hi*4 + r;
        int wh = row >> 6, pos = row & 63;
        float outv = expf(accd[ri][nb][r] - xd_s[row]) * 0.17677669529663687f;
        ushort* dst = (ushort*)(wh ? qp : kp);
        dst[((size_t)(m0+pos))*32 + m] = bfbits(outv);
      }
    }
  }
}

// ---------------- kptv (MFMA): part = v^T kp per 196-chunk; bf16 inputs
__global__ __launch_bounds__(256) void k_kptv(
    const __hip_bfloat16* __restrict__ v_g, const __hip_bfloat16* __restrict__ kp,
    float* __restrict__ part, float* __restrict__ kpsum_part)
{
  __shared__ __align__(16) ushort vT[64*232];
  __shared__ __align__(16) ushort kpT[32*232];
  __shared__ float ksh[8][32];
  const int b = blockIdx.y, g = blockIdx.x;
  const int t = threadIdx.x;
  const int w = t>>6, lane = t&63, l15 = lane&15, hi = lane>>4;
  const int t0 = g*196;
  const ushort* vu = (const ushort*)v_g;
  const ushort* ku = (const ushort*)kp;

  for (int idx = t; idx < 14336; idx += 256){
    int tt = idx >> 6, n = idx & 63;
    vT[n*232 + tt] = (tt < 196) ? vu[((size_t)b*TT + t0 + tt)*64 + n] : (ushort)0;
  }
  for (int idx = t; idx < 7168; idx += 256){
    int tt = idx >> 5, m = idx & 31;
    kpT[m*232 + tt] = (tt < 196) ? ku[((size_t)b*TT + t0 + tt)*32 + m] : (ushort)0;
  }
  __syncthreads();

  f32x4 accp[2];
  accp[0] = (f32x4){0.f,0.f,0.f,0.f};
  accp[1] = (f32x4){0.f,0.f,0.f,0.f};
  for (int ks=0; ks<7; ++ks){
    bf16x8 a = *(const bf16x8*)&vT[(w*16+l15)*232 + ks*32 + hi*8];
    #pragma unroll
    for (int nt=0; nt<2; ++nt){
      bf16x8 bv = *(const bf16x8*)&kpT[(nt*16+l15)*232 + ks*32 + hi*8];
      accp[nt] = __builtin_amdgcn_mfma_f32_16x16x32_bf16(a, bv, accp[nt], 0, 0, 0);
    }
  }
  #pragma unroll
  for (int nt=0;nt<2;++nt){
    #pragma unroll
    for (int r=0;r<4;++r){
      int row = w*16 + hi*4 + r;
      int col = nt*16 + l15;
      part[(((size_t)g*BB + b)*64 + row)*MM + col] = accp[nt][r];
    }
  }
  {
    int m = t & 31, h8 = t >> 5;
    float s = 0.f;
    int lo = h8*25, hic = lo+25 < 196 ? lo+25 : 196;
    for (int tt = lo; tt < hic; ++tt) s += bf2f(kpT[m*232 + tt]);
    ksh[h8][m] = s;
  }
  __syncthreads();
  if (t < 32){
    float s = 0.f;
    #pragma unroll
    for (int j=0;j<8;++j) s += ksh[j][t];
    kpsum_part[(size_t)g*1024 + b*32 + t] = s;
  }
}

// reduce partials -> kptvb (bf16) + kpsum (f32)
__global__ __launch_bounds__(256) void k_kptv_red(
    const float* __restrict__ part, const float* __restrict__ kpsum_part,
    __hip_bfloat16* __restrict__ kptvb, float* __restrict__ kpsum)
{
  const int t = threadIdx.x;
  const int idx = blockIdx.x*256 + t;
  float a = 0.f;
  #pragma unroll
  for (int g=0; g<16; ++g) a += part[(size_t)g*65536 + idx];
  kptvb[idx] = __float2bfloat16(a);
  if (blockIdx.x < 4){
    int kidx = blockIdx.x*256 + t;
    float s = 0.f;
    #pragma unroll
    for (int g=0; g<16; ++g) s += kpsum_part[(size_t)g*1024 + kidx];
    kpsum[kidx] = s;
  }
}

// ---------------- fused attention + proj + residuals + LN2 + MLP -> out; 64 pos/block
__global__ __launch_bounds__(256) void k_attn_mlp(
    const __hip_bfloat16* __restrict__ v_g, const __hip_bfloat16* __restrict__ qp,
    const float* __restrict__ kpsum, const __hip_bfloat16* __restrict__ kptvb,
    const __hip_bfloat16* __restrict__ wpjb, const float* __restrict__ projb,
    const __hip_bfloat16* __restrict__ convXb,
    const float* __restrict__ ln2_g, const float* __restrict__ ln2_b,
    const __hip_bfloat16* __restrict__ wm1b, const float* __restrict__ b1,
    const __hip_bfloat16* __restrict__ wm2b, const float* __restrict__ b2,
    float* __restrict__ out)
{
  __shared__ __align__(16) char smem[64512];
  ushort* qpb = (ushort*)smem;
  ushort* ktb = (ushort*)(smem + 5120);
  ushort* pjw = (ushort*)(smem + 10240);
  ushort* hb  = (ushort*)smem;
  ushort* t2  = (ushort*)(smem + 19456);
  ushort* w1b = (ushort*)(smem + 28672);
  ushort* w2b = (ushort*)(smem + 37888);
  float*  xosh= (float*)(smem + 47104);
  __shared__ float Ds[64];
  __shared__ float Dp[4][64];
  __shared__ float ks_s[32], pjb_s[64], b1_s[64], b2_s[64], g2_s[64], bb2_s[64];

  const int t = threadIdx.x;
  const int b = blockIdx.y;
  const int p0 = blockIdx.x*64;
  const int w = t>>6, lane = t&63, l15 = lane&15, hi = lane>>4;

  const ushort* qpu = (const ushort*)qp + ((size_t)b*TT + p0)*32;
  for (int idx = t; idx < 2048; idx += 256)
    qpb[(idx>>5)*40 + (idx&31)] = qpu[idx];
  const ushort* ktg = (const ushort*)kptvb + (size_t)b*2048;
  for (int idx = t; idx < 2048; idx += 256)
    ktb[(idx>>5)*40 + (idx&31)] = ktg[idx];
  const ushort* pju = (const ushort*)wpjb;
  const ushort* w1u = (const ushort*)wm1b;
  const ushort* w2u = (const ushort*)wm2b;
  for (int idx = t; idx < 4096; idx += 256){
    pjw[(idx>>6)*72 + (idx&63)] = pju[idx];
    w1b[(idx>>6)*72 + (idx&63)] = w1u[idx];
    w2b[(idx>>6)*72 + (idx&63)] = w2u[idx];
  }
  if (t < 32) ks_s[t] = kpsum[b*MM + t];
  if (t < 64){
    pjb_s[t] = projb[t]; b1_s[t] = b1[t]; b2_s[t] = b2[t];
    g2_s[t] = ln2_g[t];  bb2_s[t] = ln2_b[t];
  }
  __syncthreads();

  {
    int pos = t & 63, grp = t >> 6;
    float s = 0.f;
    #pragma unroll
    for (int j=0;j<8;++j){
      int m = grp*8 + j;
      s += bf2f(qpb[pos*40 + m]) * ks_s[m];
    }
    Dp[grp][pos] = s;
  }
  __syncthreads();
  if (t < 64) Ds[t] = Dp[0][t]+Dp[1][t]+Dp[2][t]+Dp[3][t] + 1e-8f;
  __syncthreads();

  f32x4 acc1[4];
  #pragma unroll
  for (int nb=0;nb<4;++nb) acc1[nb] = (f32x4){0.f,0.f,0.f,0.f};
  {
    bf16x8 a = *(const bf16x8*)&qpb[(w*16 + l15)*40 + hi*8];
    #pragma unroll
    for (int nb=0;nb<4;++nb){
      bf16x8 bv = *(const bf16x8*)&ktb[(nb*16 + l15)*40 + hi*8];
      acc1[nb] = __builtin_amdgcn_mfma_f32_16x16x32_bf16(a, bv, acc1[nb], 0, 0, 0);
    }
  }
  #pragma unroll
  for (int nb=0;nb<4;++nb){
    #pragma unroll
    for (int r=0;r<4;++r){
      int row = w*16 + hi*4 + r;
      t2[row*72 + nb*16 + l15] = bfbits(acc1[nb][r] / Ds[row]);
    }
  }
  __syncthreads();

  f32x4 acc2[4];
  #pragma unroll
  for (int nb=0;nb<4;++nb) acc2[nb] = (f32x4){0.f,0.f,0.f,0.f};
  #pragma unroll
  for (int ks=0; ks<2; ++ks){
    bf16x8 a2 = *(const bf16x8*)&t2[(w*16 + l15)*72 + ks*32 + hi*8];
    #pragma unroll
    for (int nb=0;nb<4;++nb){
      bf16x8 bv2 = *(const bf16x8*)&pjw[(nb*16 + l15)*72 + ks*32 + hi*8];
      acc2[nb] = __builtin_amdgcn_mfma_f32_16x16x32_bf16(a2, bv2, acc2[nb], 0, 0, 0);
    }
  }
  const ushort* cxu = (const ushort*)convXb;
  const ushort* vu  = (const ushort*)v_g;
  #pragma unroll
  for (int nb=0;nb<4;++nb){
    #pragma unroll
    for (int r=0;r<4;++r){
      int row = w*16 + hi*4 + r;
      int col = nb*16 + l15;
      const size_t off = ((size_t)b*TT + p0 + row)*64 + col;
      xosh[row*68 + col] = bf2f(vu[off]) + acc2[nb][r] + pjb_s[col] + bf2f(cxu[off]);
    }
  }
  __syncthreads();

  // LN2 (width-64 xor-shuffle) -> t2 (bf16)
  {
    const int n = t & 63, p = t >> 6;
    const float g2 = g2_s[n], bb2 = bb2_s[n];
    for (int sp=0; sp<16; ++sp){
      const int pos = sp*4 + p;
      const float xv = xosh[pos*68 + n];
      float s1 = xv, s2 = xv*xv;
      #pragma unroll
      for (int o=32;o;o>>=1){
        s1 += __shfl_xor(s1, o, 64);
        s2 += __shfl_xor(s2, o, 64);
      }
      float mu = s1*(1.f/64.f);
      float rs = rsqrtf(s2*(1.f/64.f) - mu*mu + 1e-5f);
      t2[pos*72 + n] = bfbits((xv - mu)*rs*g2 + bb2);
    }
  }
  __syncthreads();

  f32x4 acc3[4];
  #pragma unroll
  for (int nb=0;nb<4;++nb) acc3[nb] = (f32x4){0.f,0.f,0.f,0.f};
  #pragma unroll
  for (int ks=0; ks<2; ++ks){
    bf16x8 a3 = *(const bf16x8*)&t2[(w*16 + l15)*72 + ks*32 + hi*8];
    #pragma unroll
    for (int nb=0;nb<4;++nb){
      bf16x8 bv3 = *(const bf16x8*)&w1b[(nb*16 + l15)*72 + ks*32 + hi*8];
      acc3[nb] = __builtin_amdgcn_mfma_f32_16x16x32_bf16(a3, bv3, acc3[nb], 0, 0, 0);
    }
  }
  __syncthreads();
  #pragma unroll
  for (int nb=0;nb<4;++nb){
    #pragma unroll
    for (int r=0;r<4;++r){
      int row = w*16 + hi*4 + r;
      int col = nb*16 + l15;
      hb[row*72 + col] = bfbits(geluf(acc3[nb][r] + b1_s[col]));
    }
  }
  __syncthreads();

  f32x4 acc4[4];
  #pragma unroll
  for (int nb=0;nb<4;++nb) acc4[nb] = (f32x4){0.f,0.f,0.f,0.f};
  #pragma unroll
  for (int ks=0; ks<2; ++ks){
    bf16x8 a4 = *(const bf16x8*)&hb[(w*16 + l15)*72 + ks*32 + hi*8];
    #pragma unroll
    for (int nb=0;nb<4;++nb){
      bf16x8 bv4 = *(const bf16x8*)&w2b[(nb*16 + l15)*72 + ks*32 + hi*8];
      acc4[nb] = __builtin_amdgcn_mfma_f32_16x16x32_bf16(a4, bv4, acc4[nb], 0, 0, 0);
    }
  }
  #pragma unroll
  for (int nb=0;nb<4;++nb){
    #pragma unroll
    for (int r=0;r<4;++r){
      int row = w*16 + hi*4 + r;
      int col = nb*16 + l15;
      const size_t off = ((size_t)b*TT + p0 + row)*64 + col;
      out[off] = xosh[row*68 + col] + acc4[nb][r] + b2_s[col];
    }
  }
}

extern "C" void kernel_launch(void* const* d_in, const int* in_sizes, int n_in,
                              void* d_out, int out_size, void* d_ws, size_t ws_size,
                              hipStream_t stream)
{
  const float* x      = (const float*)d_in[0];
  const float* prm_w  = (const float*)d_in[1];
  const float* prm_b  = (const float*)d_in[2];
  const float* pcm_w1 = (const float*)d_in[3];
  const float* pcm_b1 = (const float*)d_in[4];
  const float* pcm_w2 = (const float*)d_in[5];
  const float* pcm_b2 = (const float*)d_in[6];
  const float* bn_g   = (const float*)d_in[7];
  const float* bn_b   = (const float*)d_in[8];
  const float* bn_mean= (const float*)d_in[9];
  const float* bn_var = (const float*)d_in[10];
  const float* pcm_w3 = (const float*)d_in[11];
  const float* pcm_b3 = (const float*)d_in[12];
  const float* ln1_g  = (const float*)d_in[13];
  const float* ln1_b  = (const float*)d_in[14];
  const float* kqv_w  = (const float*)d_in[15];
  const float* kqv_b  = (const float*)d_in[16];
  const float* w_perf = (const float*)d_in[17];
  const float* proj_w = (const float*)d_in[18];
  const float* proj_b = (const float*)d_in[19];
  const float* ln2_g  = (const float*)d_in[20];
  const float* ln2_b  = (const float*)d_in[21];
  const float* mlp_w1 = (const float*)d_in[22];
  const float* mlp_b1 = (const float*)d_in[23];
  const float* mlp_w2 = (const float*)d_in[24];
  const float* mlp_b2 = (const float*)d_in[25];

  float* ws = (float*)d_ws;
  __hip_bfloat16* convXb = (__hip_bfloat16*)(ws + OFF_CONVX);
  __hip_bfloat16* c2b = (__hip_bfloat16*)(ws + OFF_C2B);
  __hip_bfloat16* xn  = (__hip_bfloat16*)(ws + OFF_XN);
  __hip_bfloat16* c1b = (__hip_bfloat16*)(ws + OFF_C1B);
  __hip_bfloat16* v_g = (__hip_bfloat16*)(ws + OFF_V);
  __hip_bfloat16* kp  = (__hip_bfloat16*)(ws + OFF_KP);
  __hip_bfloat16* qp  = (__hip_bfloat16*)(ws + OFF_QP);
  float* part  = ws + OFF_PART;
  __hip_bfloat16* kptvb = (__hip_bfloat16*)(ws + OFF_KPTV);
  float* kpsum_part = ws + OFF_KPSP;
  float* kpsum = ws + OFF_KPSUM;
  float* wpt   = ws + OFF_WPT;
  __hip_bfloat16* wkb  = (__hip_bfloat16*)(ws + OFF_WKB);
  __hip_bfloat16* wc2b = (__hip_bfloat16*)(ws + OFF_WC2B);
  __hip_bfloat16* wt3b = (__hip_bfloat16*)(ws + OFF_WT3B);
  __hip_bfloat16* wc1b = (__hip_bfloat16*)(ws + OFF_WC1B);
  __hip_bfloat16* wpjb = (__hip_bfloat16*)(ws + OFF_WPJB);
  __hip_bfloat16* wm1b = (__hip_bfloat16*)(ws + OFF_WM1B);
  __hip_bfloat16* wm2b = (__hip_bfloat16*)(ws + OFF_WM2B);
  __hip_bfloat16* wpfh = (__hip_bfloat16*)(ws + OFF_WPFH);
  __hip_bfloat16* wpfl = (__hip_bfloat16*)(ws + OFF_WPFL);
  float* out   = (float*)d_out;

  k_wtrans<<<dim3(699), 256, 0, stream>>>(prm_w, kqv_w, pcm_w2, pcm_w3, pcm_w1,
                                          proj_w, mlp_w1, mlp_w2, w_perf,
                                          wpt, wkb, wc2b, wt3b, wc1b,
                                          wpjb, wm1b, wm2b, wpfh, wpfl);
  // CNN stem (all MFMA)
  k_conv1<<<dim3(196,BB), 256, 0, stream>>>(x, wc1b, pcm_b1, c1b);
  k_conv2<<<dim3(49,BB), 256, 0, stream>>>(c1b, wc2b, pcm_b2, bn_g, bn_b,
                                           bn_mean, bn_var, c2b);
  k_conv3<<<dim3(49,BB), 256, 0, stream>>>(c2b, wt3b, pcm_b3, convXb);
  // PRM + LN -> xn (bf16)
  k_prm_ln<<<dim3(224,BB), 256, 0, stream>>>(x, wpt, prm_b, ln1_g, ln1_b, xn);
  // KQV GEMM (MFMA) + Performer features (MFMA split dots)
  k_kqv_perf<<<dim3(1568), 256, 0, stream>>>(xn, wkb, kqv_b, wpfh, wpfl, v_g, kp, qp);
  // Performer reductions (MFMA)
  k_kptv<<<dim3(16,BB), 256, 0, stream>>>(v_g, kp, part, kpsum_part);
  k_kptv_red<<<dim3(256), 256, 0, stream>>>(part, kpsum_part, kptvb, kpsum);
  // fused attention + MLP -> out
  k_attn_mlp<<<dim3(49,BB), 256, 0, stream>>>(v_g, qp, kpsum, kptvb, wpjb, proj_b,
                                              convXb, ln2_g, ln2_b, wm1b, mlp_b1,
                                              wm2b, mlp_b2, out);
}